// Round 8
// baseline (36.757 us; speedup 1.0000x reference)
//
#include <hip/hip_runtime.h>
#include <math.h>

#define VOCAB 100000
#define EMB 128
#define BATCH 16384
#define NPOS 4
#define NNEG 20
#define EPSV 1e-3f

#define NTHREADS 256
#define WPB (NTHREADS / 64)       // 4 waves/block, one batch elem per wave
#define NBLOCKS (BATCH / WPB)     // 4096

#define INV_BP (1.0f / (float)(BATCH * NPOS))
#define INV_BN (1.0f / (float)(BATCH * NNEG))

__device__ __forceinline__ float dot4(float4 a, float4 b) {
    return a.x * b.x + a.y * b.y + a.z * b.z + a.w * b.w;
}

// One wave per batch element, (sample x chunk) layout: sg = lane>>3 owns
// sample g*8+sg, c = lane&7 owns chunks {c, c+8, c+16, c+24}.
// Dot partials accumulate in-register over chunks; cross-lane reduce is a
// 3-step shfl over the 8-lane c-group (DPP-class ops). Loss terms are
// pre-scaled by -1/(B*P) / -1/(B*N) so the whole wave reduces ONE
// accumulator (6-shfl tail instead of 12).
__global__ __launch_bounds__(NTHREADS, 4) void w2v_main(
    const int* __restrict__ x,
    const int* __restrict__ pos,
    const int* __restrict__ neg,
    const float* __restrict__ emb,
    const float* __restrict__ outw,
    float* __restrict__ partials)
{
    const int tid  = threadIdx.x;
    const int lane = tid & 63;
    const int wid  = tid >> 6;
    const int sg   = lane >> 3;   // 0..7: sample-in-group
    const int c    = lane & 7;    // 0..7: chunk lane

    const int b  = blockIdx.x * WPB + wid;  // batch element (wave-uniform)
    const int xb = x[b];

    // Sample indices for groups 0..2 (8 lanes share each address; TA dedups).
    const int idx0 = (sg < NPOS) ? pos[b * NPOS + sg] : neg[b * NNEG + (sg - NPOS)];
    const int idx1 = neg[b * NNEG + (8  + sg - NPOS)];
    const int idx2 = neg[b * NNEG + (16 + sg - NPOS)];

    // emb chunks this lane needs: c, c+8, c+16, c+24 (8-way dup per inst).
    const float4* er = (const float4*)(emb + ((long)xb << 7));
    const float4 e0 = er[c];
    const float4 e1 = er[c + 8];
    const float4 e2 = er[c + 16];
    const float4 e3 = er[c + 24];

    float d0, d1, d2;
#pragma unroll
    for (int g = 0; g < 3; ++g) {
        const int row = (g == 0) ? idx0 : ((g == 1) ? idx1 : idx2);
        const float4* wr = (const float4*)(outw + ((long)row << 7));
        const float4 w0 = wr[c];
        const float4 w1 = wr[c + 8];
        const float4 w2 = wr[c + 16];
        const float4 w3 = wr[c + 24];

        float d = dot4(e0, w0) + dot4(e1, w1) + dot4(e2, w2) + dot4(e3, w3);

        // reduce over the 8-lane c-group (masks < 8: fast DPP-class)
        d += __shfl_xor(d, 1);
        d += __shfl_xor(d, 2);
        d += __shfl_xor(d, 4);

        if      (g == 0) d0 = d;
        else if (g == 1) d1 = d;
        else             d2 = d;
    }

    // Transcendental tail spread over lanes c<3: lane c finalizes sample
    // s = c*8 + sg, with the loss scale folded in (single accumulator).
    float acc = 0.0f;
    if (c < 3) {
        const float zz = (c == 0) ? d0 : ((c == 1) ? d1 : d2);
        const int   s  = c * 8 + sg;
        const float sig = 1.0f / (1.0f + __expf(-zz));
        acc = (s < NPOS) ? (-__logf(sig) * INV_BP)
                         : (-__logf(1.0f - sig + EPSV) * INV_BN);
    }

    // wave-wide butterfly (single accumulator: 6 shfl, not 12)
#pragma unroll
    for (int m = 1; m < 64; m <<= 1)
        acc += __shfl_xor(acc, m);

    __shared__ float sp[WPB];
    if (lane == 0) sp[wid] = acc;
    __syncthreads();
    if (tid == 0)
        partials[blockIdx.x] = sp[0] + sp[1] + sp[2] + sp[3];
}

// Finalize: single block reduces 4096 float partials into the scalar loss.
__global__ __launch_bounds__(1024) void w2v_final(
    const float* __restrict__ partials, float* __restrict__ out)
{
    const int tid  = threadIdx.x;
    const int lane = tid & 63;
    const int wid  = tid >> 6;

    float t = 0.0f;
#pragma unroll
    for (int k = tid; k < NBLOCKS; k += 1024)
        t += partials[k];
#pragma unroll
    for (int m = 1; m < 64; m <<= 1)
        t += __shfl_xor(t, m);

    __shared__ float sp[16];
    if (lane == 0) sp[wid] = t;
    __syncthreads();
    if (tid == 0) {
        float s = 0.0f;
#pragma unroll
        for (int w = 0; w < 16; ++w) s += sp[w];
        out[0] = s;
    }
}

extern "C" void kernel_launch(void* const* d_in, const int* in_sizes, int n_in,
                              void* d_out, int out_size, void* d_ws, size_t ws_size,
                              hipStream_t stream) {
    const int*   x    = (const int*)d_in[0];
    const int*   pos  = (const int*)d_in[1];
    const int*   neg  = (const int*)d_in[2];
    const float* emb  = (const float*)d_in[3];
    const float* outw = (const float*)d_in[4];
    float* out = (float*)d_out;
    float* partials = (float*)d_ws;   // 4096 floats, fully rewritten each launch

    w2v_main<<<NBLOCKS, NTHREADS, 0, stream>>>(x, pos, neg, emb, outw, partials);
    w2v_final<<<1, 1024, 0, stream>>>(partials, out);
}

// Round 9
// 35.777 us; speedup vs baseline: 1.0274x; 1.0274x over previous
//
#include <hip/hip_runtime.h>
#include <math.h>

#define VOCAB 100000
#define EMB 128
#define BATCH 16384
#define NPOS 4
#define NNEG 20
#define EPSV 1e-3f

#define NTHREADS 256
#define WPB (NTHREADS / 64)        // 4 waves/block
#define EPW 2                      // batch elems per wave
#define NBLOCKS (BATCH / (WPB * EPW))   // 2048

#define INV_BP (1.0f / (float)(BATCH * NPOS))
#define INV_BN (1.0f / (float)(BATCH * NNEG))

__device__ __forceinline__ float dot4(float4 a, float4 b) {
    return a.x * b.x + a.y * b.y + a.z * b.z + a.w * b.w;
}

// 2 batch elems per wave, (sample x chunk) layout per elem:
//   sg = lane>>3 owns sample g*8+sg of the elem, c = lane&7 owns chunks
//   {c,c+8,c+16,c+24}. BOTH elems' index+emb loads issue upfront, and
//   elem1's W loads issue before elem0's reduce/transcendental tail, so the
//   two per-elem latency chains overlap inside one wave.
__global__ __launch_bounds__(NTHREADS, 2) void w2v_main(
    const int* __restrict__ x,
    const int* __restrict__ pos,
    const int* __restrict__ neg,
    const float* __restrict__ emb,
    const float* __restrict__ outw,
    float* __restrict__ partials)
{
    const int tid  = threadIdx.x;
    const int lane = tid & 63;
    const int wid  = tid >> 6;
    const int sg   = lane >> 3;   // 0..7
    const int c    = lane & 7;    // 0..7

    const int b0 = (blockIdx.x * WPB + wid) * EPW;  // first elem of this wave
    const int b1 = b0 + 1;

    // ---- upfront: indices + emb for BOTH elems ----
    const int xb0 = x[b0];
    const int xb1 = x[b1];

    const int i00 = (sg < NPOS) ? pos[b0 * NPOS + sg] : neg[b0 * NNEG + (sg - NPOS)];
    const int i01 = neg[b0 * NNEG + (8  + sg - NPOS)];
    const int i02 = neg[b0 * NNEG + (16 + sg - NPOS)];
    const int i10 = (sg < NPOS) ? pos[b1 * NPOS + sg] : neg[b1 * NNEG + (sg - NPOS)];
    const int i11 = neg[b1 * NNEG + (8  + sg - NPOS)];
    const int i12 = neg[b1 * NNEG + (16 + sg - NPOS)];

    const float4* er0 = (const float4*)(emb + ((long)xb0 << 7));
    const float4* er1 = (const float4*)(emb + ((long)xb1 << 7));
    const float4 e00 = er0[c], e01 = er0[c + 8], e02 = er0[c + 16], e03 = er0[c + 24];
    const float4 e10 = er1[c], e11 = er1[c + 8], e12 = er1[c + 16], e13 = er1[c + 24];

    float acc = 0.0f;

#pragma unroll
    for (int e = 0; e < EPW; ++e) {
        const int j0 = e ? i10 : i00;
        const int j1 = e ? i11 : i01;
        const int j2 = e ? i12 : i02;
        const float4 f0 = e ? e10 : e00;
        const float4 f1 = e ? e11 : e01;
        const float4 f2 = e ? e12 : e02;
        const float4 f3 = e ? e13 : e03;

        const float4* w0r = (const float4*)(outw + ((long)j0 << 7));
        const float4* w1r = (const float4*)(outw + ((long)j1 << 7));
        const float4* w2r = (const float4*)(outw + ((long)j2 << 7));

        // issue all 12 W loads for this elem before any use
        const float4 a0 = w0r[c], a1 = w0r[c + 8], a2 = w0r[c + 16], a3 = w0r[c + 24];
        const float4 b0v = w1r[c], b1v = w1r[c + 8], b2v = w1r[c + 16], b3v = w1r[c + 24];
        const float4 c0v = w2r[c], c1v = w2r[c + 8], c2v = w2r[c + 16], c3v = w2r[c + 24];

        float d0 = dot4(f0, a0)  + dot4(f1, a1)  + dot4(f2, a2)  + dot4(f3, a3);
        float d1 = dot4(f0, b0v) + dot4(f1, b1v) + dot4(f2, b2v) + dot4(f3, b3v);
        float d2 = dot4(f0, c0v) + dot4(f1, c1v) + dot4(f2, c2v) + dot4(f3, c3v);

        d0 += __shfl_xor(d0, 1); d0 += __shfl_xor(d0, 2); d0 += __shfl_xor(d0, 4);
        d1 += __shfl_xor(d1, 1); d1 += __shfl_xor(d1, 2); d1 += __shfl_xor(d1, 4);
        d2 += __shfl_xor(d2, 1); d2 += __shfl_xor(d2, 2); d2 += __shfl_xor(d2, 4);

        if (c < 3) {
            const float zz = (c == 0) ? d0 : ((c == 1) ? d1 : d2);
            const int   s  = c * 8 + sg;
            const float sig = 1.0f / (1.0f + __expf(-zz));
            acc += (s < NPOS) ? (-__logf(sig) * INV_BP)
                              : (-__logf(1.0f - sig + EPSV) * INV_BN);
        }
    }

    // wave-wide butterfly (single accumulator)
#pragma unroll
    for (int m = 1; m < 64; m <<= 1)
        acc += __shfl_xor(acc, m);

    __shared__ float sp[WPB];
    if (lane == 0) sp[wid] = acc;
    __syncthreads();
    if (tid == 0)
        partials[blockIdx.x] = sp[0] + sp[1] + sp[2] + sp[3];
}

// Finalize: ONE wave reduces 2048 partials (32 loads/lane, pure shfl tail).
__global__ __launch_bounds__(64) void w2v_final(
    const float* __restrict__ partials, float* __restrict__ out)
{
    const int lane = threadIdx.x;
    float t = 0.0f;
#pragma unroll
    for (int k = 0; k < NBLOCKS / 64; ++k)
        t += partials[k * 64 + lane];
#pragma unroll
    for (int m = 1; m < 64; m <<= 1)
        t += __shfl_xor(t, m);
    if (lane == 0)
        out[0] = t;
}

extern "C" void kernel_launch(void* const* d_in, const int* in_sizes, int n_in,
                              void* d_out, int out_size, void* d_ws, size_t ws_size,
                              hipStream_t stream) {
    const int*   x    = (const int*)d_in[0];
    const int*   pos  = (const int*)d_in[1];
    const int*   neg  = (const int*)d_in[2];
    const float* emb  = (const float*)d_in[3];
    const float* outw = (const float*)d_in[4];
    float* out = (float*)d_out;
    float* partials = (float*)d_ws;   // 2048 floats, fully rewritten each launch

    w2v_main<<<NBLOCKS, NTHREADS, 0, stream>>>(x, pos, neg, emb, outw, partials);
    w2v_final<<<1, 64, 0, stream>>>(partials, out);
}